// Round 7
// baseline (541.561 us; speedup 1.0000x reference)
//
#include <hip/hip_runtime.h>
#include <hip/hip_bf16.h>

typedef __attribute__((ext_vector_type(8))) short short8;
typedef __attribute__((ext_vector_type(4))) float f32x4;

constexpr int T    = 60;    // driven timesteps
constexpr int C    = 128;   // channels == hidden
constexpr int NPIX = 4096;  // samples
constexpr int H    = 128;
constexpr int GP   = 5;
constexpr int EXTRA = T - GP - 1;   // 54 autoregressive steps
constexpr int TT    = T + EXTRA;    // 114 total outputs
constexpr int LDS_STRIDE = 136;     // bf16 elems/row: 272 B, 16B-aligned
constexpr int BUFE = 16 * LDS_STRIDE;  // elems per x/h LDS buffer (4352 B)
constexpr int OS_STRIDE = 132;      // fp32 out-staging row stride
constexpr int OSB = 16 * OS_STRIDE; // floats per out-staging buffer

__device__ __forceinline__ unsigned short f2bf(float f) {
  unsigned u = __float_as_uint(f);
  u += 0x7FFF + ((u >> 16) & 1);   // round-to-nearest-even
  return (unsigned short)(u >> 16);
}
__device__ __forceinline__ float bf2f(unsigned short s) {
  return __uint_as_float(((unsigned)s) << 16);
}
__device__ __forceinline__ float fast_sigmoid(float x) {
  float e = __builtin_amdgcn_exp2f(-1.44269504f * x);
  return __builtin_amdgcn_rcpf(1.0f + e);
}
__device__ __forceinline__ float fast_tanh(float x) {
  float e = __builtin_amdgcn_exp2f(2.88539008f * x);   // exp(2x)
  return 1.0f - 2.0f * __builtin_amdgcn_rcpf(1.0f + e);
}

// ONE fully-drained barrier per step. Traffic evidence across R0..R5:
// stores issued BEFORE a same-step drain => clean HBM traffic (R0:
// 153/320 MB); stores crossing a barrier (issued post-barrier) => +245 MB
// of amplification regardless of store shape or later drains (R2/R3/R5).
// So: store pre-drain (lagged one step, see below), drain everything once.
__device__ __forceinline__ void wg_barrier_drain() {
  asm volatile("s_waitcnt vmcnt(0) lgkmcnt(0)" ::: "memory");
  __builtin_amdgcn_s_barrier();
  __builtin_amdgcn_sched_barrier(0);
}

// One WG owns 16 samples, runs all 114 steps. 8 waves; wave w owns gate
// columns {nt*128 + 16w .. +15}. Weights live in VGPRs as bf16 B-fragments
// (128 VGPRs; REQUIRES __launch_bounds__(512,2) — (512,4) caps VGPR at 64
// and spills weights: R4 = 2.78 GB fetch, 4x slower).
// Per step (single drained barrier at the END):
//   1. read os tile of step t-1 (visible: barrier passed) -> nt store,
//      issued EARLY so the ending drain sees it ~a full step later
//   2. pack x_{t+1} into xs[p^1]; issue load of x_{t+2}
//   3. MFMA from xs[p]/hs[p]; activations
//   4. write hs[p^1] + os[p^1]
//   5. drain(vm+lgkm) + barrier   (stores/loads never cross a barrier)
__global__ __launch_bounds__(512, 2) void lstm_persistent(
    const float* __restrict__ img,   // [T][C][NPIX]
    const float* __restrict__ wih,   // [4H][C]
    const float* __restrict__ whh,   // [4H][H]
    const float* __restrict__ bih,
    const float* __restrict__ bhh,
    float* __restrict__ out)         // [NPIX][TT][H]
{
  __shared__ __align__(16) unsigned short xs[2 * BUFE];
  __shared__ __align__(16) unsigned short hs[2 * BUFE];
  __shared__ __align__(16) float os[2 * OSB];

  const int tid  = threadIdx.x;
  const int lane = tid & 63;
  const int w    = tid >> 6;      // wave 0..7
  const int l15  = lane & 15;
  const int quad = lane >> 4;     // 0..3
  // XCD swizzle (bijective, 256 WGs = 8 XCDs * 32): neighbors sharing img
  // cache lines (128 B = 32 samples = 2 WGs) land on the same XCD's L2.
  const int lb   = ((int)blockIdx.x & 7) * 32 + ((int)blockIdx.x >> 3);
  const int n0   = lb * 16;
  const int hid  = w * 16 + l15;  // hidden column this lane owns

  // ---- weight fragments (B-operand: lane holds B[k=quad*8+j][n=l15]) ----
  short8 fih[4][4], fhh[4][4];
  float bias[4];
  #pragma unroll
  for (int nt = 0; nt < 4; ++nt) {
    const int col = nt * 128 + hid;
    bias[nt] = bih[col] + bhh[col];
    #pragma unroll
    for (int kt = 0; kt < 4; ++kt) {
      const int k0 = kt * 32 + quad * 8;
      const float* pih = wih + col * C + k0;
      const float* phh = whh + col * C + k0;
      short8 a, b;
      #pragma unroll
      for (int j = 0; j < 8; ++j) {
        a[j] = (short)f2bf(pih[j]);
        b[j] = (short)f2bf(phh[j]);
      }
      fih[nt][kt] = a;
      fhh[nt][kt] = b;
    }
  }

  // zero h state in buffer 0
  for (int i = tid; i < BUFE; i += 512) hs[i] = 0;

  // fp32 cell state: lane owns (sample = quad*4 + r, hid)
  float c[4] = {0.f, 0.f, 0.f, 0.f};

  // x staging: thread covers (nl = tid&15, channels cb..cb+3)
  const int nl = tid & 15;
  const int cb = (tid >> 4) * 4;
  const float* xbase = img + (size_t)cb * NPIX + n0 + nl;

  auto loadx = [&](int t) -> f32x4 {
    const float* p = xbase + (size_t)t * (C * NPIX);
    return (f32x4){p[0], p[NPIX], p[2 * NPIX], p[3 * NPIX]};
  };

  // stage x_0 into buf0
  {
    f32x4 q = loadx(0);
    ushort4 pk;
    pk.x = f2bf(q[0]); pk.y = f2bf(q[1]); pk.z = f2bf(q[2]); pk.w = f2bf(q[3]);
    *(ushort4*)&xs[nl * LDS_STRIDE + cb] = pk;
  }
  f32x4 qcur = loadx(1);   // completes at the drain below
  wg_barrier_drain();

  const int fro = l15 * LDS_STRIDE + quad * 8;  // A-frag element offset

  // coalesced out-store mapping: thread covers (sample ss, cols c4..c4+3);
  // 32 consecutive lanes write 512 B contiguous = 4 FULL 128-B lines.
  const int ss = tid >> 5;          // sample 0..15
  const int c4 = (tid & 31) * 4;    // hid column 0,4,..,124
  const int osr = ss * OS_STRIDE + c4;
  float* osp = out + (size_t)(n0 + ss) * ((size_t)TT * H) + c4;  // +H per store

  // step t (sb = t&1): store step t-1's tile from os[sb], pack x_{t+1} into
  // xs[sb^1], compute from xs[sb]/hs[sb], write hs[sb^1]/os[sb^1], drain.
  auto step_drv = [&](int sb, bool dopack, f32x4 qpk, bool dostore) {
    const int so  = sb ? BUFE : 0;
    const int dso = sb ? 0 : BUFE;
    const int ros = sb ? OSB : 0;
    const int wos = sb ? 0 : OSB;
    if (dostore) {   // lagged store: tile of step t-1, issued early
      f32x4 v = *(const f32x4*)&os[ros + osr];
      __builtin_nontemporal_store(v, (f32x4*)osp);
      osp += H;
    }
    if (dopack) {    // x_{t+1} -> buffer used by step t+1
      ushort4 pk;
      pk.x = f2bf(qpk[0]); pk.y = f2bf(qpk[1]); pk.z = f2bf(qpk[2]); pk.w = f2bf(qpk[3]);
      *(ushort4*)&xs[dso + nl * LDS_STRIDE + cb] = pk;
    }
    f32x4 acc[4];
    #pragma unroll
    for (int nt = 0; nt < 4; ++nt)
      acc[nt] = (f32x4){bias[nt], bias[nt], bias[nt], bias[nt]};
    #pragma unroll
    for (int kt = 0; kt < 4; ++kt) {
      short8 ax = *(const short8*)&xs[so + fro + kt * 32];
      short8 ah = *(const short8*)&hs[so + fro + kt * 32];
      #pragma unroll
      for (int nt = 0; nt < 4; ++nt) {
        acc[nt] = __builtin_amdgcn_mfma_f32_16x16x32_bf16(ax, fih[nt][kt], acc[nt], 0, 0, 0);
        acc[nt] = __builtin_amdgcn_mfma_f32_16x16x32_bf16(ah, fhh[nt][kt], acc[nt], 0, 0, 0);
      }
    }
    float hv[4];
    #pragma unroll
    for (int r = 0; r < 4; ++r) {
      float ig = fast_sigmoid(acc[0][r]);
      float fg = fast_sigmoid(acc[1][r]);
      float gg = fast_tanh(acc[2][r]);
      float og = fast_sigmoid(acc[3][r]);
      c[r] = fg * c[r] + ig * gg;
      hv[r] = og * fast_tanh(c[r]);
    }
    #pragma unroll
    for (int r = 0; r < 4; ++r) {
      hs[dso + (quad * 4 + r) * LDS_STRIDE + hid] = f2bf(hv[r]);
      os[wos + (quad * 4 + r) * OS_STRIDE + hid] = hv[r];
    }
    wg_barrier_drain();
  };

  // AR step: h feeds back as x; fih holds folded (Wih+Whh) by then
  auto step_ar = [&](int sb) {
    const int so  = sb ? BUFE : 0;
    const int dso = sb ? 0 : BUFE;
    const int ros = sb ? OSB : 0;
    const int wos = sb ? 0 : OSB;
    {
      f32x4 v = *(const f32x4*)&os[ros + osr];
      __builtin_nontemporal_store(v, (f32x4*)osp);
      osp += H;
    }
    f32x4 acc[4];
    #pragma unroll
    for (int nt = 0; nt < 4; ++nt)
      acc[nt] = (f32x4){bias[nt], bias[nt], bias[nt], bias[nt]};
    #pragma unroll
    for (int kt = 0; kt < 4; ++kt) {
      short8 ah = *(const short8*)&hs[so + fro + kt * 32];
      #pragma unroll
      for (int nt = 0; nt < 4; ++nt)
        acc[nt] = __builtin_amdgcn_mfma_f32_16x16x32_bf16(ah, fih[nt][kt], acc[nt], 0, 0, 0);
    }
    float hv[4];
    #pragma unroll
    for (int r = 0; r < 4; ++r) {
      float ig = fast_sigmoid(acc[0][r]);
      float fg = fast_sigmoid(acc[1][r]);
      float gg = fast_tanh(acc[2][r]);
      float og = fast_sigmoid(acc[3][r]);
      c[r] = fg * c[r] + ig * gg;
      hv[r] = og * fast_tanh(c[r]);
    }
    #pragma unroll
    for (int r = 0; r < 4; ++r) {
      hs[dso + (quad * 4 + r) * LDS_STRIDE + hid] = f2bf(hv[r]);
      os[wos + (quad * 4 + r) * OS_STRIDE + hid] = hv[r];
    }
    wg_barrier_drain();
  };

  // ---- driven phase: qcur entering step t holds x_{t+1}; a load issued at
  // step t completes at that step's ending drain. ----
  {                                     // t=0: pack x1, load x2, no store yet
    f32x4 qn = loadx(2);
    step_drv(0, true, qcur, false);
    qcur = qn;
  }
  {                                     // t=1: pack x2, load x3, store t0
    f32x4 qn = loadx(3);
    step_drv(1, true, qcur, true);
    qcur = qn;
  }
  #pragma unroll 1
  for (int t = 2; t < T - 4; t += 2) {  // t = 2,4,..,54 -> steps 2..55
    f32x4 qa = loadx(t + 2);
    step_drv(0, true, qcur, true);
    f32x4 qb = loadx(t + 3);
    step_drv(1, true, qa, true);
    qcur = qb;
  }
  {                                     // t=56: pack x57, load x58
    f32x4 qa = loadx(58);
    step_drv(0, true, qcur, true);
    qcur = qa;
  }
  {                                     // t=57: pack x58, load x59
    f32x4 qa = loadx(59);
    step_drv(1, true, qcur, true);
    qcur = qa;
  }
  step_drv(0, true, qcur, true);        // t=58: pack x59
  step_drv(1, false, qcur, true);       // t=59: no pack

  // ---- fold W_sum = W_ih + W_hh into fih (registers only, no sync) ----
  #pragma unroll
  for (int nt = 0; nt < 4; ++nt)
    #pragma unroll
    for (int kt = 0; kt < 4; ++kt) {
      short8 a = fih[nt][kt], b = fhh[nt][kt];
      #pragma unroll
      for (int j = 0; j < 8; ++j)
        a[j] = (short)f2bf(bf2f((unsigned short)a[j]) + bf2f((unsigned short)b[j]));
      fih[nt][kt] = a;
    }

  // ---- AR phase: steps 60..113; 60&1==0 so parity continues seamlessly ----
  #pragma unroll 1
  for (int t = 0; t < EXTRA; t += 2) {
    step_ar(0);
    step_ar(1);
  }

  // flush the final step's tile (step 113 wrote os[0]; barrier passed)
  {
    f32x4 v = *(const f32x4*)&os[0 + osr];
    __builtin_nontemporal_store(v, (f32x4*)osp);
  }
}

extern "C" void kernel_launch(void* const* d_in, const int* in_sizes, int n_in,
                              void* d_out, int out_size, void* d_ws, size_t ws_size,
                              hipStream_t stream) {
  (void)in_sizes; (void)n_in; (void)d_ws; (void)ws_size; (void)out_size;
  const float* img = (const float*)d_in[0];
  // d_in[1] = mask (unused by reference forward)
  const float* wih = (const float*)d_in[2];
  const float* whh = (const float*)d_in[3];
  const float* bih = (const float*)d_in[4];
  const float* bhh = (const float*)d_in[5];
  // d_in[6] = gp_affected_timesteps (static = 5, baked into EXTRA)
  float* out = (float*)d_out;

  lstm_persistent<<<NPIX / 16, 512, 0, stream>>>(img, wih, whh, bih, bhh, out);
}